// Round 4
// baseline (259.404 us; speedup 1.0000x reference)
//
#include <hip/hip_runtime.h>
#include <hip/hip_bf16.h>

#define LOG2E 1.4426950408889634f

typedef __bf16 bf16x8 __attribute__((ext_vector_type(8)));
typedef float  f32x4  __attribute__((ext_vector_type(4)));

// 2 f32 -> packed 2x bf16 (RNE); compiler emits v_cvt_pk_bf16_f32
__device__ inline unsigned pack2(float lo, float hi){
  __hip_bfloat162 h = __float22bfloat162_rn(make_float2(lo, hi));
  return *reinterpret_cast<unsigned*>(&h);
}

// Monotonic ticket grid-barrier (no reset needed across iterations/replays).
// Safe: 256 blocks x (1024 thr, 72KB LDS, <=128 VGPR) -> 1 block/CU on 256 CUs,
// all blocks co-resident by construction. Agent-scope fences handle XCD L2s.
__device__ unsigned g_bar;   // zero-initialized at module load

__device__ inline void grid_barrier(){
  __threadfence();                                   // release: L2 writeback
  __syncthreads();
  if (threadIdx.x == 0){
    unsigned ticket = __hip_atomic_fetch_add(&g_bar, 1u, __ATOMIC_ACQ_REL,
                                             __HIP_MEMORY_SCOPE_AGENT);
    unsigned target = (ticket / 256u + 1u) * 256u;
    while (__hip_atomic_load(&g_bar, __ATOMIC_ACQUIRE,
                             __HIP_MEMORY_SCOPE_AGENT) < target)
      __builtin_amdgcn_s_sleep(2);
  }
  __syncthreads();
  __threadfence();                                   // acquire: L1/L2 invalidate
}

// Fused: phase 1 = round-3 K1 (K-split GEMM, one-shot staging, b-major P),
// grid barrier, phase 2 = round-3 K2 (pairwise exp(-L1)).  One launch total.
// bid -> phase1 (mt = bid&3, nt = (bid>>2)&15, ks = bid>>6)
//     -> phase2 (b = bid>>2, jc = bid&3)
__global__ __launch_bounds__(1024) void k_fused(const float* __restrict__ X,
                                                const float* __restrict__ Wm,
                                                const float* __restrict__ bias,
                                                float* __restrict__ out,
                                                float* __restrict__ P){
  __shared__ __align__(16) char smem[73728];         // 72 KB, reused across phases
  unsigned short* As = (unsigned short*)smem;            // [4][64*72] bf16
  unsigned short* Bs = (unsigned short*)(smem + 36864);  // [4][64*72] bf16, swizzled

  const int bid = blockIdx.x;
  const int t = threadIdx.x;
  const int lane = t & 63, w = t >> 6;
  const int r16 = lane & 15, quad = lane >> 4;

  { // ================= phase 1: GEMM partials =================
    const int m0 = (bid & 3) * 64, n0 = ((bid >> 2) & 15) * 64;
    const int ks = bid >> 6, k0 = ks * 256;
    const int g = t >> 8, s = t & 255;        // k-chunk group, index within group
    const int wrow = (w & 3) * 16, wcol = (w >> 2) * 16;

    const int ar = s >> 2, aq = s & 3;        // A: row 0..63, 16-float quarter
    const int bc = s & 15, bg = s >> 4;       // B: 4-col group, 4-krow group
    const float* ap = X + (size_t)(m0 + ar) * 1024 + k0 + g * 64 + aq * 16;
    const float* bp = Wm + (size_t)(k0 + g * 64) * 1024 + n0 + bc * 4;

    float4 pa[4], pb[4];
    #pragma unroll
    for (int r = 0; r < 4; ++r) pa[r] = *(const float4*)(ap + r * 4);
    #pragma unroll
    for (int r = 0; r < 4; ++r) pb[r] = *(const float4*)(bp + (size_t)(4 * bg + r) * 1024);

    { // A tile: 16 floats -> 16 bf16, contiguous store
      unsigned short* d = &As[g * 4608 + ar * 72 + aq * 16];
      uint4 o;
      o.x = pack2(pa[0].x, pa[0].y); o.y = pack2(pa[0].z, pa[0].w);
      o.z = pack2(pa[1].x, pa[1].y); o.w = pack2(pa[1].z, pa[1].w);
      *(uint4*)d = o;
      o.x = pack2(pa[2].x, pa[2].y); o.y = pack2(pa[2].z, pa[2].w);
      o.z = pack2(pa[3].x, pa[3].y); o.w = pack2(pa[3].z, pa[3].w);
      *(uint4*)(d + 8) = o;
    }
    { // B tile: transpose 4 k-rows x 4 n-cols into [n][k], swizzled 8-bf16 chunks
      #pragma unroll
      for (int e = 0; e < 4; ++e){
        const int n = bc * 4 + e;
        uint2 o;
        o.x = pack2(((const float*)&pb[0])[e], ((const float*)&pb[1])[e]);
        o.y = pack2(((const float*)&pb[2])[e], ((const float*)&pb[3])[e]);
        const int cw = (bg >> 1) ^ ((n >> 3) & 7);
        *(uint2*)(&Bs[g * 4608 + n * 72 + cw * 8 + (bg & 1) * 4]) = o;
      }
    }
    __syncthreads();

    f32x4 acc0, acc1;
    #pragma unroll
    for (int e = 0; e < 4; ++e){ acc0[e] = 0.f; acc1[e] = 0.f; }
    const int nn = wcol + r16;
    const int nsw = (nn >> 3) & 7;
    #pragma unroll
    for (int gg = 0; gg < 4; ++gg){
      bf16x8 a0 = *(const bf16x8*)(&As[gg * 4608 + (wrow + r16) * 72 + quad * 8]);
      bf16x8 a1 = *(const bf16x8*)(&As[gg * 4608 + (wrow + r16) * 72 + 32 + quad * 8]);
      bf16x8 b0 = *(const bf16x8*)(&Bs[gg * 4608 + nn * 72 + (((quad    ) ^ nsw) * 8)]);
      bf16x8 b1 = *(const bf16x8*)(&Bs[gg * 4608 + nn * 72 + (((quad + 4) ^ nsw) * 8)]);
      acc0 = __builtin_amdgcn_mfma_f32_16x16x32_bf16(a0, b0, acc0, 0, 0, 0);
      acc1 = __builtin_amdgcn_mfma_f32_16x16x32_bf16(a1, b1, acc1, 0, 0, 0);
    }
    // C/D layout (verified): col = lane&15, row = (lane>>4)*4 + reg
    // b-major: P[ks][col>>4][row][col&15]
    float* Pz = P + (size_t)ks * 262144 + (size_t)((n0 + wcol) >> 4) * 4096;
    #pragma unroll
    for (int r = 0; r < 4; ++r){
      const int row = m0 + wrow + quad * 4 + r;
      Pz[row * 16 + r16] = acc0[r] + acc1[r];
    }
  }

  grid_barrier();

  { // ================= phase 2: pairwise exp(-L1) =================
    float* L   = (float*)smem;                 // [256][20], stride 20
    float* red = (float*)(smem + 20480);       // [16][64]
    const int b = bid >> 2, jc = bid & 3;

    { // stage + reduce K-split partials: thread -> one float4 of L (coalesced)
      const int i = t >> 2, q = t & 3;
      const float* base = P + (size_t)b * 4096 + t * 4;
      float4 s0 = *(const float4*)(base);
      float4 s1 = *(const float4*)(base + 262144);
      float4 s2 = *(const float4*)(base + 524288);
      float4 s3 = *(const float4*)(base + 786432);
      float4 r;
      r.x = (s0.x + s1.x) + (s2.x + s3.x);
      r.y = (s0.y + s1.y) + (s2.y + s3.y);
      r.z = (s0.z + s1.z) + (s2.z + s3.z);
      r.w = (s0.w + s1.w) + (s2.w + s3.w);
      *(float4*)(&L[i * 20 + q * 4]) = r;
    }
    __syncthreads();

    const int j = jc * 64 + lane;
    float oj[16];
    #pragma unroll
    for (int q = 0; q < 4; ++q){
      float4 v = *(const float4*)(&L[j * 20 + q * 4]);
      oj[q*4+0] = v.x; oj[q*4+1] = v.y; oj[q*4+2] = v.z; oj[q*4+3] = v.w;
    }

    float acc = 0.f;
    const int i0 = w * 16;
    #pragma unroll 4
    for (int ii = i0; ii < i0 + 16; ++ii){
      const float4* fr = (const float4*)(&L[ii * 20]);   // wave-uniform -> broadcast
      float4 f0 = fr[0], f1 = fr[1], f2 = fr[2], f3 = fr[3];
      float p0 = fabsf(oj[0]  - f0.x) + fabsf(oj[1]  - f0.y)
               + fabsf(oj[2]  - f0.z) + fabsf(oj[3]  - f0.w);
      float p1 = fabsf(oj[4]  - f1.x) + fabsf(oj[5]  - f1.y)
               + fabsf(oj[6]  - f1.z) + fabsf(oj[7]  - f1.w);
      float p2 = fabsf(oj[8]  - f2.x) + fabsf(oj[9]  - f2.y)
               + fabsf(oj[10] - f2.z) + fabsf(oj[11] - f2.w);
      float p3 = fabsf(oj[12] - f3.x) + fabsf(oj[13] - f3.y)
               + fabsf(oj[14] - f3.z) + fabsf(oj[15] - f3.w);
      acc += exp2f(-LOG2E * ((p0 + p1) + (p2 + p3)));
    }
    red[w * 64 + lane] = acc;
    __syncthreads();
    if (w == 0){
      float tot = 0.f;
      #pragma unroll
      for (int ww = 0; ww < 16; ++ww) tot += red[ww * 64 + lane];
      out[(size_t)j * 64 + b] = tot + bias[b];
    }
  }
}

extern "C" void kernel_launch(void* const* d_in, const int* in_sizes, int n_in,
                              void* d_out, int out_size, void* d_ws, size_t ws_size,
                              hipStream_t stream){
  const float* x    = (const float*)d_in[0];   // [256][1024]
  const float* W    = (const float*)d_in[1];   // [1024][1024] k-major
  const float* bias = (const float*)d_in[2];   // [64]
  float* out = (float*)d_out;                  // [256][64]
  float* P   = (float*)d_ws;                   // 4 MB: partial [4][64][256][16]

  k_fused<<<256, 1024, 0, stream>>>(x, W, bias, out, P);
}

// Round 5
// 73.110 us; speedup vs baseline: 3.5481x; 3.5481x over previous
//
#include <hip/hip_runtime.h>
#include <hip/hip_bf16.h>

#define LOG2E 1.4426950408889634f

typedef __bf16 bf16x8 __attribute__((ext_vector_type(8)));
typedef float  f32x4  __attribute__((ext_vector_type(4)));

// 2 f32 -> packed 2x bf16 (RNE); compiler emits v_cvt_pk_bf16_f32
__device__ inline unsigned pack2(float lo, float hi){
  __hip_bfloat162 h = __float22bfloat162_rn(make_float2(lo, hi));
  return *reinterpret_cast<unsigned*>(&h);
}

// ---- K1: full-K GEMM -> mat, b-major P[64][256][16] f32 (1 MB, no K-split).
// grid (32 nt, 8 mt) x 1024 thr; tile 32m x 32n; K=1024 staged ONE-SHOT:
//   As 16x[32][72] bf16 (72 KB), Bs 16x[32][72] bf16 XOR-chunk swizzled (72 KB).
// 16 waves = 4 out-tiles (2m x 2n) x 4 K-quarters; 12 KB LDS cross-wave reduce
// (aliased over As after compute). blockIdx.x = nt -> all mt-blocks of an nt
// share an XCD (bid%8 = nt%8), so the 4 MB W is fetched once per XCD.
__global__ __launch_bounds__(1024) void k_gemm(const float* __restrict__ X,
                                               const float* __restrict__ Wm,
                                               float* __restrict__ P){
  __shared__ __align__(16) char smem[147456];            // 144 KB
  unsigned short* As = (unsigned short*)smem;            // [16 chunk][32 m][72]
  unsigned short* Bs = (unsigned short*)(smem + 73728);  // [16 chunk][32 n][72], swizzled
  float* red = (float*)smem;                             // aliased: [3][4][64] f32x4

  const int nt = blockIdx.x, mt = blockIdx.y;
  const int m0 = mt * 32, n0 = nt * 32;
  const int t = threadIdx.x, lane = t & 63, w = t >> 6;
  const int r16 = lane & 15, quad = lane >> 4;

  { // ---- stage A: X[m0..+32][0..1024) -> bf16, chunked [k/64][m][k%64]
    const int ar = t >> 5, aq = t & 31;        // row, 32-float k-segment
    const float* ap = X + (size_t)(m0 + ar) * 1024 + aq * 32;
    float4 pa[8];
    #pragma unroll
    for (int h = 0; h < 8; ++h) pa[h] = *(const float4*)(ap + h * 4);
    unsigned short* d = &As[(aq >> 1) * 2304 + ar * 72 + (aq & 1) * 32];
    #pragma unroll
    for (int h = 0; h < 4; ++h){
      uint4 o;
      o.x = pack2(pa[2*h  ].x, pa[2*h  ].y); o.y = pack2(pa[2*h  ].z, pa[2*h  ].w);
      o.z = pack2(pa[2*h+1].x, pa[2*h+1].y); o.w = pack2(pa[2*h+1].z, pa[2*h+1].w);
      *(uint4*)(d + h * 8) = o;
    }
  }
  { // ---- stage B: W[0..1024)[n0..+32) -> [n][k] bf16, XOR-chunk swizzle
    const int bc = t & 7, bg = t >> 3;         // 4-col group, 8-krow group
    const float* bp = Wm + (size_t)(8 * bg) * 1024 + n0 + bc * 4;
    float4 pb[8];
    #pragma unroll
    for (int r = 0; r < 8; ++r) pb[r] = *(const float4*)(bp + (size_t)r * 1024);
    const int chunk = bg >> 3, slot = bg & 7;
    #pragma unroll
    for (int e = 0; e < 4; ++e){
      const int n = bc * 4 + e;
      const int cw = slot ^ ((n >> 3) & 7);
      uint4 o;
      o.x = pack2(((const float*)&pb[0])[e], ((const float*)&pb[1])[e]);
      o.y = pack2(((const float*)&pb[2])[e], ((const float*)&pb[3])[e]);
      o.z = pack2(((const float*)&pb[4])[e], ((const float*)&pb[5])[e]);
      o.w = pack2(((const float*)&pb[6])[e], ((const float*)&pb[7])[e]);
      *(uint4*)(&Bs[chunk * 2304 + n * 72 + cw * 8]) = o;
    }
  }
  __syncthreads();

  // ---- compute: wave w -> out-tile tq (2m x 2n), K-quarter kq
  const int tq = w & 3, kq = w >> 2;
  const int mrow = (tq & 1) * 16 + r16;        // A row in tile
  const int nn   = (tq >> 1) * 16 + r16;       // B row (n) in tile
  const int nsw  = (nn >> 3) & 7;
  f32x4 acc0, acc1;
  #pragma unroll
  for (int e = 0; e < 4; ++e){ acc0[e] = 0.f; acc1[e] = 0.f; }
  #pragma unroll
  for (int s = 0; s < 8; s += 2){
    int ko = kq * 256 + s * 32 + quad * 8;
    int ch = ko >> 6, off = ko & 63;
    bf16x8 a0 = *(const bf16x8*)(&As[ch * 2304 + mrow * 72 + off]);
    bf16x8 b0 = *(const bf16x8*)(&Bs[ch * 2304 + nn * 72 + (((off >> 3) ^ nsw) * 8)]);
    acc0 = __builtin_amdgcn_mfma_f32_16x16x32_bf16(a0, b0, acc0, 0, 0, 0);
    ko += 32; ch = ko >> 6; off = ko & 63;
    bf16x8 a1 = *(const bf16x8*)(&As[ch * 2304 + mrow * 72 + off]);
    bf16x8 b1 = *(const bf16x8*)(&Bs[ch * 2304 + nn * 72 + (((off >> 3) ^ nsw) * 8)]);
    acc1 = __builtin_amdgcn_mfma_f32_16x16x32_bf16(a1, b1, acc1, 0, 0, 0);
  }
  f32x4 sum;
  #pragma unroll
  for (int e = 0; e < 4; ++e) sum[e] = acc0[e] + acc1[e];

  __syncthreads();                             // all As/Bs reads complete
  if (kq){
    *(f32x4*)(&red[(((kq - 1) * 4 + tq) * 64 + lane) * 4]) = sum;
  }
  __syncthreads();
  if (kq == 0){
    f32x4 r0 = *(const f32x4*)(&red[((0 * 4 + tq) * 64 + lane) * 4]);
    f32x4 r1 = *(const f32x4*)(&red[((1 * 4 + tq) * 64 + lane) * 4]);
    f32x4 r2 = *(const f32x4*)(&red[((2 * 4 + tq) * 64 + lane) * 4]);
    #pragma unroll
    for (int e = 0; e < 4; ++e) sum[e] += (r0[e] + r1[e]) + r2[e];
    // C/D layout (verified): col = lane&15, row = (lane>>4)*4 + reg
    const int b = nt * 2 + (tq >> 1);
    float* Pb = P + (size_t)b * 4096;
    #pragma unroll
    for (int e = 0; e < 4; ++e){
      const int row = m0 + (tq & 1) * 16 + quad * 4 + e;
      Pb[row * 16 + r16] = sum[e];
    }
  }
}

// ---- K2: out[j][b] = bias[b] + sum_i exp(-sum_c |mat[i,b,c]-mat[j,b,c]|)
// grid 256 = 64 b * 4 j-chunks; 1024 thr = 16 waves; wave w owns i in [w*16,+16).
// Staging is ONE contiguous 16 KB stream per block (b-major mat).
__global__ __launch_bounds__(1024) void k_pair(const float* __restrict__ P,
                                               const float* __restrict__ bias,
                                               float* __restrict__ out){
  __shared__ float L[256 * 20];     // mat[:, b*16 .. b*16+16), row stride 20
  __shared__ float red[16][64];
  const int b = blockIdx.x >> 2, jc = blockIdx.x & 3;
  const int t = threadIdx.x, lane = t & 63, w = t >> 6;

  { // stage: thread -> one float4 of L (fully coalesced single stream)
    const int i = t >> 2, q = t & 3;
    float4 r = *(const float4*)(P + (size_t)b * 4096 + t * 4);
    *(float4*)(&L[i * 20 + q * 4]) = r;
  }
  __syncthreads();

  const int j = jc * 64 + lane;
  float oj[16];
  #pragma unroll
  for (int q = 0; q < 4; ++q){
    float4 v = *(const float4*)(&L[j * 20 + q * 4]);
    oj[q*4+0] = v.x; oj[q*4+1] = v.y; oj[q*4+2] = v.z; oj[q*4+3] = v.w;
  }

  float acc = 0.f;
  const int i0 = w * 16;
  #pragma unroll 4
  for (int ii = i0; ii < i0 + 16; ++ii){
    const float4* fr = (const float4*)(&L[ii * 20]);   // wave-uniform -> broadcast
    float4 f0 = fr[0], f1 = fr[1], f2 = fr[2], f3 = fr[3];
    float p0 = fabsf(oj[0]  - f0.x) + fabsf(oj[1]  - f0.y)
             + fabsf(oj[2]  - f0.z) + fabsf(oj[3]  - f0.w);
    float p1 = fabsf(oj[4]  - f1.x) + fabsf(oj[5]  - f1.y)
             + fabsf(oj[6]  - f1.z) + fabsf(oj[7]  - f1.w);
    float p2 = fabsf(oj[8]  - f2.x) + fabsf(oj[9]  - f2.y)
             + fabsf(oj[10] - f2.z) + fabsf(oj[11] - f2.w);
    float p3 = fabsf(oj[12] - f3.x) + fabsf(oj[13] - f3.y)
             + fabsf(oj[14] - f3.z) + fabsf(oj[15] - f3.w);
    acc += exp2f(-LOG2E * ((p0 + p1) + (p2 + p3)));
  }
  red[w][lane] = acc;
  __syncthreads();
  if (w == 0){
    float tot = 0.f;
    #pragma unroll
    for (int ww = 0; ww < 16; ++ww) tot += red[ww][lane];
    out[(size_t)j * 64 + b] = tot + bias[b];
  }
}

extern "C" void kernel_launch(void* const* d_in, const int* in_sizes, int n_in,
                              void* d_out, int out_size, void* d_ws, size_t ws_size,
                              hipStream_t stream){
  const float* x    = (const float*)d_in[0];   // [256][1024]
  const float* W    = (const float*)d_in[1];   // [1024][1024] k-major
  const float* bias = (const float*)d_in[2];   // [64]
  float* out = (float*)d_out;                  // [256][64]
  float* P   = (float*)d_ws;                   // 1 MB: mat b-major [64][256][16]

  k_gemm<<<dim3(32, 8), 1024, 0, stream>>>(x, W, P);
  k_pair<<<256, 1024, 0, stream>>>(P, bias, out);
}